// Round 1
// baseline (3830.996 us; speedup 1.0000x reference)
//
#include <hip/hip_runtime.h>
#include <math.h>

// Sliced Wasserstein-2: for each (b,c,p): W2^2 = mean_i (sort(X@theta_p) - sort(Y@theta_p))^2
// loss = mean_{b,c} sqrt(mean_p W2^2)
//
// Structure: 1 workgroup per (b,c,p). Project slice into 128KB LDS, bitonic sort,
// park sorted X in registers, re-sort Y in the same LDS, accumulate squared diffs.

namespace {
constexpr int Bb = 8, Cc = 4, Nn = 32768, Pp = 50;
constexpr int THREADS = 1024;
constexpr int VPT = Nn / THREADS;          // 32 values per thread
constexpr int SLICES = Bb * Cc * Pp;       // 1600
}

__device__ __forceinline__ void bitonic_sort_lds(float* s, int tid) {
  for (int k = 2; k <= Nn; k <<= 1) {
    for (int j = k >> 1; j > 0; j >>= 1) {
#pragma unroll 1
      for (int t = tid; t < Nn / 2; t += THREADS) {
        // t-th compare pair for stride j: insert a 0 bit at position log2(j)
        int i  = ((t & ~(j - 1)) << 1) | (t & (j - 1));
        int pi = i | j;
        float a = s[i];
        float b = s[pi];
        float mn = fminf(a, b);
        float mx = fmaxf(a, b);
        bool up = (i & k) == 0;          // ascending block?
        s[i]  = up ? mn : mx;            // unconditional writes: no divergence
        s[pi] = up ? mx : mn;
      }
      __syncthreads();
    }
  }
}

extern "C" __global__ void __launch_bounds__(THREADS)
swd_slice(const float* __restrict__ x, const float* __restrict__ y,
          const float* __restrict__ proj, float* __restrict__ w2) {
  extern __shared__ float s[];               // Nn floats = 128 KB
  __shared__ float wsum[THREADS / 64];
  const int slice = blockIdx.x;              // [0, SLICES)
  const int p  = slice % Pp;
  const int bc = slice / Pp;
  const int tid = threadIdx.x;
  const float t0 = proj[2 * p];
  const float t1 = proj[2 * p + 1];
  const float2* xb = (const float2*)x + (size_t)bc * Nn;  // D=2 -> float2/elem
  const float2* yb = (const float2*)y + (size_t)bc * Nn;

  // ---- project X slice onto theta_p, sort ----
#pragma unroll 1
  for (int i = tid; i < Nn; i += THREADS) {
    float2 v = xb[i];
    s[i] = fmaf(v.x, t0, v.y * t1);
  }
  __syncthreads();
  bitonic_sort_lds(s, tid);

  // park sorted X in registers; strided mapping -> conflict-free LDS reads
  float sx[VPT];
#pragma unroll
  for (int k = 0; k < VPT; k++) sx[k] = s[tid + k * THREADS];
  __syncthreads();

  // ---- project Y slice, sort ----
#pragma unroll 1
  for (int i = tid; i < Nn; i += THREADS) {
    float2 v = yb[i];
    s[i] = fmaf(v.x, t0, v.y * t1);
  }
  __syncthreads();
  bitonic_sort_lds(s, tid);

  // ---- sum of squared diffs of matched order statistics ----
  float acc = 0.f;
#pragma unroll
  for (int k = 0; k < VPT; k++) {
    float d = sx[k] - s[tid + k * THREADS];
    acc = fmaf(d, d, acc);
  }
#pragma unroll
  for (int off = 32; off > 0; off >>= 1)
    acc += __shfl_down(acc, off, 64);
  if ((tid & 63) == 0) wsum[tid >> 6] = acc;
  __syncthreads();
  if (tid == 0) {
    float t = 0.f;
#pragma unroll
    for (int w = 0; w < THREADS / 64; w++) t += wsum[w];
    w2[slice] = t * (1.0f / Nn);             // mean over N
  }
}

extern "C" __global__ void swd_final(const float* __restrict__ w2,
                                     float* __restrict__ out) {
  __shared__ float sred[Bb * Cc];
  int t = threadIdx.x;
  if (t < Bb * Cc) {
    float sum = 0.f;
    for (int p = 0; p < Pp; p++) sum += w2[t * Pp + p];
    sred[t] = sqrtf(sum * (1.0f / Pp));      // SWD per (b,c)
  }
  __syncthreads();
  if (t == 0) {
    float a = 0.f;
    for (int i = 0; i < Bb * Cc; i++) a += sred[i];
    out[0] = a * (1.0f / (Bb * Cc));         // mean over slices
  }
}

extern "C" void kernel_launch(void* const* d_in, const int* in_sizes, int n_in,
                              void* d_out, int out_size, void* d_ws, size_t ws_size,
                              hipStream_t stream) {
  const float* x    = (const float*)d_in[0];   // output [B,C,N,D] fp32
  const float* y    = (const float*)d_in[1];   // target [B,C,N,D] fp32
  const float* proj = (const float*)d_in[2];   // projections [P,D] fp32
  float* w2  = (float*)d_ws;                   // [SLICES] fp32 scratch
  float* out = (float*)d_out;

  // opt in to >64KB dynamic LDS (gfx950: 160 KB/CU); idempotent, capture-safe
  (void)hipFuncSetAttribute((const void*)swd_slice,
                            hipFuncAttributeMaxDynamicSharedMemorySize,
                            Nn * (int)sizeof(float));

  hipLaunchKernelGGL(swd_slice, dim3(SLICES), dim3(THREADS),
                     Nn * sizeof(float), stream, x, y, proj, w2);
  hipLaunchKernelGGL(swd_final, dim3(1), dim3(64), 0, stream, w2, out);
}

// Round 2
// 2078.195 us; speedup vs baseline: 1.8434x; 1.8434x over previous
//
#include <hip/hip_runtime.h>
#include <math.h>

// Sliced Wasserstein-2: for each (b,c,p): W2^2 = mean_i (sort(X@theta_p) - sort(Y@theta_p))^2
// loss = mean_{b,c} sqrt(mean_p W2^2)
//
// R2: register-resident bitonic sort. Element i = tid*32 + r lives in register r of
// thread tid. Stages with j<=16 are in-register (65/120), j=32..1024 via __shfl_xor
// within the wave (45/120), only j>=2048 (10/120) go through LDS (conflict-free
// column layout). Sorted X stays in registers across the Y sort.

namespace {
constexpr int Bb = 8, Cc = 4, Nn = 32768, Pp = 50;
constexpr int THREADS = 1024;
constexpr int VPT = 32;                    // values per thread
constexpr int SLICES = Bb * Cc * Pp;       // 1600
}

__device__ __forceinline__ void ce(float& a, float& b, bool up) {
  float lo = fminf(a, b);
  float hi = fmaxf(a, b);
  a = up ? lo : hi;
  b = up ? hi : lo;
}

// Full bitonic sort of the distributed array v[] (32768 elems over 1024 threads).
// s = 128KB LDS scratch for the 10 wave-crossing stages.
__device__ __forceinline__ void sort_dist(float v[VPT], float* s, int tid) {
  // ---- phase 1: k = 2..32, all j <= 16 in-register ----
#pragma unroll
  for (int k = 2; k <= VPT; k <<= 1) {
#pragma unroll
    for (int j = k >> 1; j > 0; j >>= 1) {
#pragma unroll
      for (int r = 0; r < VPT; r++) {
        if ((r & j) == 0) {
          // k<=16: direction is a compile-time function of r; k=32: tid bit 0
          bool up = (((tid * VPT + r) & k) == 0);
          ce(v[r], v[r | j], up);
        }
      }
    }
  }
  // ---- phase 2: k = 64..32768 ----
  for (int k = 64; k <= Nn; k <<= 1) {
    const bool up = (((tid * VPT) & k) == 0);   // uniform over this thread's 32 elems
    // cross-thread stages: j = k/2 .. 32
    for (int j = k >> 1; j >= VPT; j >>= 1) {
      const int m = j / VPT;                    // partner tid xor-mask, 1..512
      const bool keepMin = (up == ((tid & m) == 0));
      if (m < 64) {
        // partner in same wave64: shuffle exchange, no barrier, no bank conflicts
#pragma unroll
        for (int r = 0; r < VPT; r++) {
          float o = __shfl_xor(v[r], m, 64);
          v[r] = keepMin ? fminf(v[r], o) : fmaxf(v[r], o);
        }
      } else {
        // wave-crossing: LDS exchange, column layout s[r*THREADS + tid]
        __syncthreads();                        // prior stage's reads must finish
#pragma unroll
        for (int r = 0; r < VPT; r++) s[r * THREADS + tid] = v[r];
        __syncthreads();
        const int pt = tid ^ m;
#pragma unroll
        for (int r = 0; r < VPT; r++) {
          float o = s[r * THREADS + pt];
          v[r] = keepMin ? fminf(v[r], o) : fmaxf(v[r], o);
        }
      }
    }
    // in-register tail: j = 16..1, direction uniform per thread
#pragma unroll
    for (int j = VPT >> 1; j > 0; j >>= 1) {
#pragma unroll
      for (int r = 0; r < VPT; r++) {
        if ((r & j) == 0) ce(v[r], v[r | j], up);
      }
    }
  }
}

extern "C" __global__ void __launch_bounds__(THREADS)
swd_slice(const float* __restrict__ x, const float* __restrict__ y,
          const float* __restrict__ proj, float* __restrict__ w2) {
  extern __shared__ float s[];               // Nn floats = 128 KB
  __shared__ float wsum[THREADS / 64];
  const int slice = blockIdx.x;
  const int p  = slice % Pp;
  const int bc = slice / Pp;
  const int tid = threadIdx.x;
  const float t0 = proj[2 * p];
  const float t1 = proj[2 * p + 1];
  // D=2: one float4 = two consecutive points
  const float4* xb = (const float4*)(x + (size_t)bc * Nn * 2);
  const float4* yb = (const float4*)(y + (size_t)bc * Nn * 2);

  float v[VPT], sx[VPT];

  // ---- project X (thread t owns points tid*32 .. tid*32+31), sort ----
#pragma unroll
  for (int q = 0; q < VPT / 2; q++) {
    float4 u = xb[tid * (VPT / 2) + q];
    v[2 * q]     = fmaf(u.x, t0, u.y * t1);
    v[2 * q + 1] = fmaf(u.z, t0, u.w * t1);
  }
  sort_dist(v, s, tid);
#pragma unroll
  for (int r = 0; r < VPT; r++) sx[r] = v[r];   // sorted X stays in registers

  // ---- project Y, sort ----
#pragma unroll
  for (int q = 0; q < VPT / 2; q++) {
    float4 u = yb[tid * (VPT / 2) + q];
    v[2 * q]     = fmaf(u.x, t0, u.y * t1);
    v[2 * q + 1] = fmaf(u.z, t0, u.w * t1);
  }
  sort_dist(v, s, tid);

  // ---- sum of squared diffs of matched order statistics ----
  float acc = 0.f;
#pragma unroll
  for (int r = 0; r < VPT; r++) {
    float d = sx[r] - v[r];
    acc = fmaf(d, d, acc);
  }
#pragma unroll
  for (int off = 32; off > 0; off >>= 1)
    acc += __shfl_down(acc, off, 64);
  if ((tid & 63) == 0) wsum[tid >> 6] = acc;
  __syncthreads();
  if (tid == 0) {
    float t = 0.f;
#pragma unroll
    for (int w = 0; w < THREADS / 64; w++) t += wsum[w];
    w2[slice] = t * (1.0f / Nn);               // mean over N
  }
}

extern "C" __global__ void swd_final(const float* __restrict__ w2,
                                     float* __restrict__ out) {
  __shared__ float sred[Bb * Cc];
  int t = threadIdx.x;
  if (t < Bb * Cc) {
    float sum = 0.f;
    for (int p = 0; p < Pp; p++) sum += w2[t * Pp + p];
    sred[t] = sqrtf(sum * (1.0f / Pp));        // SWD per (b,c)
  }
  __syncthreads();
  if (t == 0) {
    float a = 0.f;
    for (int i = 0; i < Bb * Cc; i++) a += sred[i];
    out[0] = a * (1.0f / (Bb * Cc));           // mean over (b,c)
  }
}

extern "C" void kernel_launch(void* const* d_in, const int* in_sizes, int n_in,
                              void* d_out, int out_size, void* d_ws, size_t ws_size,
                              hipStream_t stream) {
  const float* x    = (const float*)d_in[0];   // output [B,C,N,D] fp32
  const float* y    = (const float*)d_in[1];   // target [B,C,N,D] fp32
  const float* proj = (const float*)d_in[2];   // projections [P,D] fp32
  float* w2  = (float*)d_ws;                   // [SLICES] fp32 scratch
  float* out = (float*)d_out;

  (void)hipFuncSetAttribute((const void*)swd_slice,
                            hipFuncAttributeMaxDynamicSharedMemorySize,
                            Nn * (int)sizeof(float));

  hipLaunchKernelGGL(swd_slice, dim3(SLICES), dim3(THREADS),
                     Nn * sizeof(float), stream, x, y, proj, w2);
  hipLaunchKernelGGL(swd_final, dim3(1), dim3(64), 0, stream, w2, out);
}

// Round 3
// 2078.024 us; speedup vs baseline: 1.8436x; 1.0001x over previous
//
#include <hip/hip_runtime.h>
#include <math.h>

// Sliced Wasserstein-2: for each (b,c,p): W2^2 = mean_i (sort(X@theta_p) - sort(Y@theta_p))^2
// loss = mean_{b,c} sqrt(mean_p W2^2)
//
// R3: same register-resident bitonic as R2, but __launch_bounds__(1024, 4):
// the 128KB dynamic LDS already caps occupancy at 1 block/CU, so let the
// compiler use 128 VGPRs/wave instead of spilling v[32]+sx[32] to scratch
// (R2 showed VGPR=64 + 1.3GB/dispatch of spill traffic).

namespace {
constexpr int Bb = 8, Cc = 4, Nn = 32768, Pp = 50;
constexpr int THREADS = 1024;
constexpr int VPT = 32;                    // values per thread
constexpr int SLICES = Bb * Cc * Pp;       // 1600
}

__device__ __forceinline__ void ce(float& a, float& b, bool up) {
  float lo = fminf(a, b);
  float hi = fmaxf(a, b);
  a = up ? lo : hi;
  b = up ? hi : lo;
}

// Full bitonic sort of the distributed array v[] (32768 elems over 1024 threads).
// s = 128KB LDS scratch for the 10 wave-crossing stages.
__device__ __forceinline__ void sort_dist(float v[VPT], float* s, int tid) {
  // ---- phase 1: k = 2..32, all j <= 16 in-register ----
#pragma unroll
  for (int k = 2; k <= VPT; k <<= 1) {
#pragma unroll
    for (int j = k >> 1; j > 0; j >>= 1) {
#pragma unroll
      for (int r = 0; r < VPT; r++) {
        if ((r & j) == 0) {
          bool up = (((tid * VPT + r) & k) == 0);
          ce(v[r], v[r | j], up);
        }
      }
    }
  }
  // ---- phase 2: k = 64..32768 ----
  for (int k = 64; k <= Nn; k <<= 1) {
    const bool up = (((tid * VPT) & k) == 0);   // uniform over this thread's 32 elems
    // cross-thread stages: j = k/2 .. 32
    for (int j = k >> 1; j >= VPT; j >>= 1) {
      const int m = j / VPT;                    // partner tid xor-mask, 1..512
      const bool keepMin = (up == ((tid & m) == 0));
      if (m < 64) {
        // partner in same wave64: shuffle exchange, no barrier, no bank conflicts
#pragma unroll
        for (int r = 0; r < VPT; r++) {
          float o = __shfl_xor(v[r], m, 64);
          v[r] = keepMin ? fminf(v[r], o) : fmaxf(v[r], o);
        }
      } else {
        // wave-crossing: LDS exchange, column layout s[r*THREADS + tid]
        __syncthreads();                        // prior stage's reads must finish
#pragma unroll
        for (int r = 0; r < VPT; r++) s[r * THREADS + tid] = v[r];
        __syncthreads();
        const int pt = tid ^ m;
#pragma unroll
        for (int r = 0; r < VPT; r++) {
          float o = s[r * THREADS + pt];
          v[r] = keepMin ? fminf(v[r], o) : fmaxf(v[r], o);
        }
      }
    }
    // in-register tail: j = 16..1, direction uniform per thread
#pragma unroll
    for (int j = VPT >> 1; j > 0; j >>= 1) {
#pragma unroll
      for (int r = 0; r < VPT; r++) {
        if ((r & j) == 0) ce(v[r], v[r | j], up);
      }
    }
  }
}

extern "C" __global__ void __launch_bounds__(THREADS, 4)
swd_slice(const float* __restrict__ x, const float* __restrict__ y,
          const float* __restrict__ proj, float* __restrict__ w2) {
  extern __shared__ float s[];               // Nn floats = 128 KB
  __shared__ float wsum[THREADS / 64];
  const int slice = blockIdx.x;
  const int p  = slice % Pp;
  const int bc = slice / Pp;
  const int tid = threadIdx.x;
  const float t0 = proj[2 * p];
  const float t1 = proj[2 * p + 1];
  // D=2: one float4 = two consecutive points
  const float4* xb = (const float4*)(x + (size_t)bc * Nn * 2);
  const float4* yb = (const float4*)(y + (size_t)bc * Nn * 2);

  float v[VPT], sx[VPT];

  // ---- project X (thread t owns points tid*32 .. tid*32+31), sort ----
#pragma unroll
  for (int q = 0; q < VPT / 2; q++) {
    float4 u = xb[tid * (VPT / 2) + q];
    v[2 * q]     = fmaf(u.x, t0, u.y * t1);
    v[2 * q + 1] = fmaf(u.z, t0, u.w * t1);
  }
  sort_dist(v, s, tid);
#pragma unroll
  for (int r = 0; r < VPT; r++) sx[r] = v[r];   // sorted X stays in registers

  // ---- project Y, sort ----
#pragma unroll
  for (int q = 0; q < VPT / 2; q++) {
    float4 u = yb[tid * (VPT / 2) + q];
    v[2 * q]     = fmaf(u.x, t0, u.y * t1);
    v[2 * q + 1] = fmaf(u.z, t0, u.w * t1);
  }
  sort_dist(v, s, tid);

  // ---- sum of squared diffs of matched order statistics ----
  float acc = 0.f;
#pragma unroll
  for (int r = 0; r < VPT; r++) {
    float d = sx[r] - v[r];
    acc = fmaf(d, d, acc);
  }
#pragma unroll
  for (int off = 32; off > 0; off >>= 1)
    acc += __shfl_down(acc, off, 64);
  if ((tid & 63) == 0) wsum[tid >> 6] = acc;
  __syncthreads();
  if (tid == 0) {
    float t = 0.f;
#pragma unroll
    for (int w = 0; w < THREADS / 64; w++) t += wsum[w];
    w2[slice] = t * (1.0f / Nn);               // mean over N
  }
}

extern "C" __global__ void swd_final(const float* __restrict__ w2,
                                     float* __restrict__ out) {
  __shared__ float sred[Bb * Cc];
  int t = threadIdx.x;
  if (t < Bb * Cc) {
    float sum = 0.f;
    for (int p = 0; p < Pp; p++) sum += w2[t * Pp + p];
    sred[t] = sqrtf(sum * (1.0f / Pp));        // SWD per (b,c)
  }
  __syncthreads();
  if (t == 0) {
    float a = 0.f;
    for (int i = 0; i < Bb * Cc; i++) a += sred[i];
    out[0] = a * (1.0f / (Bb * Cc));           // mean over (b,c)
  }
}

extern "C" void kernel_launch(void* const* d_in, const int* in_sizes, int n_in,
                              void* d_out, int out_size, void* d_ws, size_t ws_size,
                              hipStream_t stream) {
  const float* x    = (const float*)d_in[0];   // output [B,C,N,D] fp32
  const float* y    = (const float*)d_in[1];   // target [B,C,N,D] fp32
  const float* proj = (const float*)d_in[2];   // projections [P,D] fp32
  float* w2  = (float*)d_ws;                   // [SLICES] fp32 scratch
  float* out = (float*)d_out;

  (void)hipFuncSetAttribute((const void*)swd_slice,
                            hipFuncAttributeMaxDynamicSharedMemorySize,
                            Nn * (int)sizeof(float));

  hipLaunchKernelGGL(swd_slice, dim3(SLICES), dim3(THREADS),
                     Nn * sizeof(float), stream, x, y, proj, w2);
  hipLaunchKernelGGL(swd_final, dim3(1), dim3(64), 0, stream, w2, out);
}

// Round 4
// 2075.465 us; speedup vs baseline: 1.8458x; 1.0012x over previous
//
#include <hip/hip_runtime.h>
#include <math.h>

// Sliced Wasserstein-2: for each (b,c,p): W2^2 = mean_i (sort(X@theta_p) - sort(Y@theta_p))^2
// loss = mean_{b,c} sqrt(mean_p W2^2)
//
// R4: register-resident bitonic (R2) + amdgpu_waves_per_eu(4,4) to pin the
// backend's occupancy target at 4 waves/EU (= 1 block/CU, which 128KB LDS
// forces anyway). R2/R3 showed the default heuristic targets 8 waves/EU ->
// 64 VGPRs -> 1.37 GB/dispatch of scratch spill = the whole runtime.
// launch_bounds' 2nd arg only sets the MIN waves/EU, hence R3 was neutral.

namespace {
constexpr int Bb = 8, Cc = 4, Nn = 32768, Pp = 50;
constexpr int THREADS = 1024;
constexpr int VPT = 32;                    // values per thread
constexpr int SLICES = Bb * Cc * Pp;       // 1600
}

__device__ __forceinline__ void ce(float& a, float& b, bool up) {
  float lo = fminf(a, b);
  float hi = fmaxf(a, b);
  a = up ? lo : hi;
  b = up ? hi : lo;
}

// Full bitonic sort of the distributed array v[] (32768 elems over 1024 threads).
// s = 128KB LDS scratch for the 10 wave-crossing stages.
__device__ __forceinline__ void sort_dist(float v[VPT], float* s, int tid) {
  // ---- phase 1: k = 2..32, all j <= 16 in-register ----
#pragma unroll
  for (int k = 2; k <= VPT; k <<= 1) {
#pragma unroll
    for (int j = k >> 1; j > 0; j >>= 1) {
#pragma unroll
      for (int r = 0; r < VPT; r++) {
        if ((r & j) == 0) {
          bool up = (((tid * VPT + r) & k) == 0);
          ce(v[r], v[r | j], up);
        }
      }
    }
  }
  // ---- phase 2: k = 64..32768 ----
  for (int k = 64; k <= Nn; k <<= 1) {
    const bool up = (((tid * VPT) & k) == 0);   // uniform over this thread's 32 elems
    // cross-thread stages: j = k/2 .. 32
    for (int j = k >> 1; j >= VPT; j >>= 1) {
      const int m = j / VPT;                    // partner tid xor-mask, 1..512
      const bool keepMin = (up == ((tid & m) == 0));
      if (m < 64) {
        // partner in same wave64: shuffle exchange, no barrier, no bank conflicts
#pragma unroll
        for (int r = 0; r < VPT; r++) {
          float o = __shfl_xor(v[r], m, 64);
          v[r] = keepMin ? fminf(v[r], o) : fmaxf(v[r], o);
        }
      } else {
        // wave-crossing: LDS exchange, column layout s[r*THREADS + tid]
        __syncthreads();                        // prior stage's reads must finish
#pragma unroll
        for (int r = 0; r < VPT; r++) s[r * THREADS + tid] = v[r];
        __syncthreads();
        const int pt = tid ^ m;
#pragma unroll
        for (int r = 0; r < VPT; r++) {
          float o = s[r * THREADS + pt];
          v[r] = keepMin ? fminf(v[r], o) : fmaxf(v[r], o);
        }
      }
    }
    // in-register tail: j = 16..1, direction uniform per thread
#pragma unroll
    for (int j = VPT >> 1; j > 0; j >>= 1) {
#pragma unroll
      for (int r = 0; r < VPT; r++) {
        if ((r & j) == 0) ce(v[r], v[r | j], up);
      }
    }
  }
}

extern "C" __global__
__attribute__((amdgpu_flat_work_group_size(1024, 1024), amdgpu_waves_per_eu(4, 4)))
void swd_slice(const float* __restrict__ x, const float* __restrict__ y,
               const float* __restrict__ proj, float* __restrict__ w2) {
  extern __shared__ float s[];               // Nn floats = 128 KB
  __shared__ float wsum[THREADS / 64];
  const int slice = blockIdx.x;
  const int p  = slice % Pp;
  const int bc = slice / Pp;
  const int tid = threadIdx.x;
  const float t0 = proj[2 * p];
  const float t1 = proj[2 * p + 1];
  // D=2: one float4 = two consecutive points
  const float4* xb = (const float4*)(x + (size_t)bc * Nn * 2);
  const float4* yb = (const float4*)(y + (size_t)bc * Nn * 2);

  float v[VPT], sx[VPT];

  // ---- project X (thread t owns points tid*32 .. tid*32+31), sort ----
#pragma unroll
  for (int q = 0; q < VPT / 2; q++) {
    float4 u = xb[tid * (VPT / 2) + q];
    v[2 * q]     = fmaf(u.x, t0, u.y * t1);
    v[2 * q + 1] = fmaf(u.z, t0, u.w * t1);
  }
  sort_dist(v, s, tid);
#pragma unroll
  for (int r = 0; r < VPT; r++) sx[r] = v[r];   // sorted X stays in registers

  // ---- project Y, sort ----
#pragma unroll
  for (int q = 0; q < VPT / 2; q++) {
    float4 u = yb[tid * (VPT / 2) + q];
    v[2 * q]     = fmaf(u.x, t0, u.y * t1);
    v[2 * q + 1] = fmaf(u.z, t0, u.w * t1);
  }
  sort_dist(v, s, tid);

  // ---- sum of squared diffs of matched order statistics ----
  float acc = 0.f;
#pragma unroll
  for (int r = 0; r < VPT; r++) {
    float d = sx[r] - v[r];
    acc = fmaf(d, d, acc);
  }
#pragma unroll
  for (int off = 32; off > 0; off >>= 1)
    acc += __shfl_down(acc, off, 64);
  if ((tid & 63) == 0) wsum[tid >> 6] = acc;
  __syncthreads();
  if (tid == 0) {
    float t = 0.f;
#pragma unroll
    for (int w = 0; w < THREADS / 64; w++) t += wsum[w];
    w2[slice] = t * (1.0f / Nn);               // mean over N
  }
}

extern "C" __global__ void swd_final(const float* __restrict__ w2,
                                     float* __restrict__ out) {
  __shared__ float sred[Bb * Cc];
  int t = threadIdx.x;
  if (t < Bb * Cc) {
    float sum = 0.f;
    for (int p = 0; p < Pp; p++) sum += w2[t * Pp + p];
    sred[t] = sqrtf(sum * (1.0f / Pp));        // SWD per (b,c)
  }
  __syncthreads();
  if (t == 0) {
    float a = 0.f;
    for (int i = 0; i < Bb * Cc; i++) a += sred[i];
    out[0] = a * (1.0f / (Bb * Cc));           // mean over (b,c)
  }
}

extern "C" void kernel_launch(void* const* d_in, const int* in_sizes, int n_in,
                              void* d_out, int out_size, void* d_ws, size_t ws_size,
                              hipStream_t stream) {
  const float* x    = (const float*)d_in[0];   // output [B,C,N,D] fp32
  const float* y    = (const float*)d_in[1];   // target [B,C,N,D] fp32
  const float* proj = (const float*)d_in[2];   // projections [P,D] fp32
  float* w2  = (float*)d_ws;                   // [SLICES] fp32 scratch
  float* out = (float*)d_out;

  (void)hipFuncSetAttribute((const void*)swd_slice,
                            hipFuncAttributeMaxDynamicSharedMemorySize,
                            Nn * (int)sizeof(float));

  hipLaunchKernelGGL(swd_slice, dim3(SLICES), dim3(THREADS),
                     Nn * sizeof(float), stream, x, y, proj, w2);
  hipLaunchKernelGGL(swd_final, dim3(1), dim3(64), 0, stream, w2, out);
}